// Round 1
// baseline (1189.550 us; speedup 1.0000x reference)
//
#include <hip/hip_runtime.h>
#include <math.h>

#define VOCAB 32000
#define TLEN  512
#define NROWS (16 * 512)

__global__ void init_out_kernel(float* out) {
    if (threadIdx.x == 0) out[0] = 0.0f;
}

__global__ __launch_bounds__(256) void seqcel_kernel(
    const float* __restrict__ preds,
    const int*   __restrict__ targets,
    const int*   __restrict__ label_sizes,
    float*       __restrict__ out)
{
    const int row = blockIdx.x;        // row = b*TLEN + t
    const int b   = row >> 9;          // TLEN = 512
    const int t   = row & (TLEN - 1);

    if (t >= label_sizes[b]) return;   // inactive row: never touch the 128 KB

    const float4* __restrict__ rowp =
        (const float4*)(preds + (size_t)row * VOCAB);
    const int n4 = VOCAB / 4;          // 8000 float4s

    // Online softmax: running max m, running sum s of exp(x - m)
    float m = -INFINITY;
    float s = 0.0f;
    for (int i = threadIdx.x; i < n4; i += 256) {
        float4 v = rowp[i];
        float lm = fmaxf(fmaxf(v.x, v.y), fmaxf(v.z, v.w));
        if (lm > m) { s *= __expf(m - lm); m = lm; }
        s += __expf(v.x - m) + __expf(v.y - m)
           + __expf(v.z - m) + __expf(v.w - m);
    }

    // Wave-64 reduction of (m, s) pairs
    #pragma unroll
    for (int off = 32; off > 0; off >>= 1) {
        float mo = __shfl_down(m, off, 64);
        float so = __shfl_down(s, off, 64);
        float nm = fmaxf(m, mo);
        s = s * __expf(m - nm) + so * __expf(mo - nm);
        m = nm;
    }

    // Cross-wave combine (4 waves per 256-thread block)
    __shared__ float sm[4], ss[4];
    const int lane = threadIdx.x & 63;
    const int wid  = threadIdx.x >> 6;
    if (lane == 0) { sm[wid] = m; ss[wid] = s; }
    __syncthreads();

    if (threadIdx.x == 0) {
        float M = sm[0], S = ss[0];
        #pragma unroll
        for (int w = 1; w < 4; ++w) {
            float nm = fmaxf(M, sm[w]);
            S = S * __expf(M - nm) + ss[w] * __expf(sm[w] - nm);
            M = nm;
        }
        const int tgt = targets[row];
        const float xt = preds[(size_t)row * VOCAB + tgt];
        const float nll = logf(S) + M - xt;   // -(xt - M - log S)
        atomicAdd(out, nll);
    }
}

extern "C" void kernel_launch(void* const* d_in, const int* in_sizes, int n_in,
                              void* d_out, int out_size, void* d_ws, size_t ws_size,
                              hipStream_t stream) {
    const float* preds       = (const float*)d_in[0];
    const int*   targets     = (const int*)d_in[1];
    const int*   label_sizes = (const int*)d_in[2];
    float*       out         = (float*)d_out;

    init_out_kernel<<<1, 64, 0, stream>>>(out);
    seqcel_kernel<<<NROWS, 256, 0, stream>>>(preds, targets, label_sizes, out);
}